// Round 2
// baseline (620.156 us; speedup 1.0000x reference)
//
#include <hip/hip_runtime.h>
#include <cstdint>
#include <cstddef>

// ---------------- CSR build ----------------
__global__ void count_edges_k(const int* __restrict__ dst, int E, int* __restrict__ cnt) {
  int e = blockIdx.x * blockDim.x + threadIdx.x;
  if (e < E) atomicAdd(&cnt[dst[e]], 1);
}

__global__ void scan1_k(const int* __restrict__ cnt, int* __restrict__ rs,
                        int* __restrict__ partials, int n) {
  __shared__ int s[1024];
  int t = threadIdx.x;
  int gid = blockIdx.x * 1024 + t;
  int v = (gid < n) ? cnt[gid] : 0;
  s[t] = v;
  __syncthreads();
  for (int off = 1; off < 1024; off <<= 1) {
    int u = (t >= off) ? s[t - off] : 0;
    __syncthreads();
    s[t] += u;
    __syncthreads();
  }
  if (gid < n) rs[gid] = s[t] - v;            // block-local exclusive scan
  if (t == 1023) partials[blockIdx.x] = s[1023];
}

__global__ void scan2_k(int* __restrict__ partials, int nb) {
  if (threadIdx.x == 0 && blockIdx.x == 0) {
    int acc = 0;
    for (int i = 0; i < nb; i++) { int v = partials[i]; partials[i] = acc; acc += v; }
  }
}

__global__ void scan3_k(int* __restrict__ rs, int* __restrict__ cursor,
                        const int* __restrict__ partials, int n, int total) {
  int gid = blockIdx.x * blockDim.x + threadIdx.x;
  if (gid < n) {
    int v = rs[gid] + partials[gid >> 10];
    rs[gid] = v;
    cursor[gid] = v;
  }
  if (gid == 0) rs[n] = total;
}

__global__ void dinv_k(const int* __restrict__ cnt, float* __restrict__ dinv, int n) {
  int i = blockIdx.x * blockDim.x + threadIdx.x;
  if (i < n) dinv[i] = rsqrtf((float)cnt[i] + 1.0f);   // +1 = self loop; deg>=1 always
}

// col stored as CT (ushort when N<=65535): 3.2MB scattered instead of 12.8MB
template <typename CT>
__global__ void fill_csr_k(const int* __restrict__ src, const int* __restrict__ dst, int E,
                           int* __restrict__ cursor, CT* __restrict__ col) {
  int e = blockIdx.x * blockDim.x + threadIdx.x;
  if (e < E) {
    int d = dst[e], s = src[e];
    int pos = atomicAdd(&cursor[d], 1);
    col[pos] = (CT)s;
  }
}

// ---------------- dense GEMM: C[N,128] = A[N,128] @ W[128,128] ----------------
__global__ __launch_bounds__(256) void gemm_k(const float* __restrict__ A,
                                              const float* __restrict__ W,
                                              float* __restrict__ C, int N) {
  __shared__ float Ws[128 * 64];
  __shared__ float As[32][132];
  const int c0 = blockIdx.y * 64;
  const int r0 = blockIdx.x * 32;
  {
    const float4* W4 = (const float4*)W;
    float4* Ws4 = (float4*)Ws;
    for (int idx = threadIdx.x; idx < 2048; idx += 256) {
      int k = idx >> 4;
      int c4 = idx & 15;
      Ws4[idx] = W4[k * 32 + (c0 >> 2) + c4];
    }
  }
  for (int idx = threadIdx.x; idx < 1024; idx += 256) {
    int rr = idx >> 5;
    int c4 = idx & 31;
    int r = r0 + rr;
    float4 v = make_float4(0.f, 0.f, 0.f, 0.f);
    if (r < N) v = ((const float4*)(A + (size_t)r * 128))[c4];
    *(float4*)&As[rr][c4 * 4] = v;
  }
  __syncthreads();
  const int tx = threadIdx.x & 15;
  const int ty = threadIdx.x >> 4;
  float acc[2][4] = {};
  #pragma unroll 8
  for (int k = 0; k < 128; k++) {
    float4 wv = *(const float4*)&Ws[k * 64 + tx * 4];
    float a0 = As[ty * 2 + 0][k];
    float a1 = As[ty * 2 + 1][k];
    acc[0][0] += a0 * wv.x; acc[0][1] += a0 * wv.y; acc[0][2] += a0 * wv.z; acc[0][3] += a0 * wv.w;
    acc[1][0] += a1 * wv.x; acc[1][1] += a1 * wv.y; acc[1][2] += a1 * wv.z; acc[1][3] += a1 * wv.w;
  }
  #pragma unroll
  for (int i = 0; i < 2; i++) {
    int r = r0 + ty * 2 + i;
    if (r < N) {
      float4 o = make_float4(acc[i][0], acc[i][1], acc[i][2], acc[i][3]);
      *(float4*)(C + (size_t)r * 128 + c0 + tx * 4) = o;
    }
  }
}

// ---------------- neighbor aggregation (CSR gather-reduce, one wave per node) ----------------
// norm folding: out = di * ( h[self]*di + sum_s h[s]*dinv[s] ), since norm = dinv[s]*dinv[dst]
template <typename CT>
__global__ __launch_bounds__(256) void agg_k(const float* __restrict__ h,
                                             const int* __restrict__ rs,
                                             const CT* __restrict__ col,
                                             const float* __restrict__ dinv,
                                             const float* __restrict__ bias,
                                             float* __restrict__ out, int n) {
  int wid = (blockIdx.x * blockDim.x + threadIdx.x) >> 6;
  int lane = threadIdx.x & 63;
  if (wid >= n) return;
  float di = dinv[wid];
  const float* hrow = h + (size_t)wid * 128;
  float acc0 = hrow[lane] * di;          // self loop (second di applied at end)
  float acc1 = hrow[64 + lane] * di;
  int beg = rs[wid], end = rs[wid + 1];
  for (int base = beg; base < end; base += 64) {
    int m = end - base; if (m > 64) m = 64;
    int sidx = 0; float w = 0.f;
    if (lane < m) { sidx = (int)col[base + lane]; w = dinv[sidx]; }
    for (int j = 0; j < m; j++) {
      int s = __shfl(sidx, j);
      float nv = __shfl(w, j);
      const float* hs = h + (size_t)s * 128;
      acc0 += hs[lane] * nv;
      acc1 += hs[64 + lane] * nv;
    }
  }
  out[(size_t)wid * 128 + lane] = fmaxf(acc0 * di + bias[lane], 0.f);
  out[(size_t)wid * 128 + 64 + lane] = fmaxf(acc1 * di + bias[64 + lane], 0.f);
}

// ---------------- per-graph mean pool ----------------
__global__ void pool_k(const float* __restrict__ h, const int* __restrict__ batch, int n,
                       float* __restrict__ pool, float* __restrict__ gcnt) {
  int f = threadIdx.x;
  int n0 = blockIdx.x * 64;
  if (n0 >= n) return;
  int n1 = n0 + 64; if (n1 > n) n1 = n;
  int gcur = batch[n0];
  float acc = 0.f, cacc = 0.f;
  for (int i = n0; i < n1; i++) {
    int g = batch[i];
    if (g != gcur) {
      atomicAdd(&pool[gcur * 128 + f], acc);
      if (f == 0) atomicAdd(&gcnt[gcur], cacc);
      acc = 0.f; cacc = 0.f; gcur = g;
    }
    acc += h[(size_t)i * 128 + f];
    cacc += 1.f;
  }
  atomicAdd(&pool[gcur * 128 + f], acc);
  if (f == 0) atomicAdd(&gcnt[gcur], cacc);
}

// ---------------- classifier head ----------------
__global__ void classify_k(const float* __restrict__ pool, const float* __restrict__ gcnt,
                           const float* __restrict__ Wc1, const float* __restrict__ bc1,
                           const float* __restrict__ Wc2, const float* __restrict__ bc2,
                           float* __restrict__ out, int nc) {
  __shared__ float gs[128];
  __shared__ float zs[128];
  int g = blockIdx.x, t = threadIdx.x;
  float c = gcnt[g]; if (c < 1.f) c = 1.f;
  gs[t] = pool[g * 128 + t] / c;
  __syncthreads();
  float acc = bc1[t];
  for (int k = 0; k < 128; k++) acc += gs[k] * Wc1[k * 128 + t];
  zs[t] = fmaxf(acc, 0.f);
  __syncthreads();
  if (t < nc) {
    float o = bc2[t];
    for (int k = 0; k < 128; k++) o += zs[k] * Wc2[k * nc + t];
    out[g * nc + t] = o;
  }
}

extern "C" void kernel_launch(void* const* d_in, const int* in_sizes, int n_in,
                              void* d_out, int out_size, void* d_ws, size_t ws_size,
                              hipStream_t stream) {
  const float* x   = (const float*)d_in[0];
  const int*   ei  = (const int*)d_in[1];
  const int*   bat = (const int*)d_in[2];
  const float* W1  = (const float*)d_in[3];
  const float* b1  = (const float*)d_in[4];
  const float* W2  = (const float*)d_in[5];
  const float* b2  = (const float*)d_in[6];
  const float* Wc1 = (const float*)d_in[7];
  const float* bc1 = (const float*)d_in[8];
  const float* Wc2 = (const float*)d_in[9];
  const float* bc2 = (const float*)d_in[10];
  float* out = (float*)d_out;

  const int N  = in_sizes[0] / 128;
  const int E  = in_sizes[1] / 2;
  const int NC = in_sizes[10];
  const int G  = out_size / NC;
  const int* src = ei;
  const int* dst = ei + E;
  (void)n_in; (void)ws_size;

  size_t off = 0;
  auto walloc = [&](size_t bytes) -> void* {
    void* p = (char*)d_ws + off;
    off += (bytes + 255) & ~(size_t)255;
    return p;
  };
  float* bufA   = (float*)walloc((size_t)N * 128 * 4);
  float* bufB   = (float*)walloc((size_t)N * 128 * 4);
  float* dinv   = (float*)walloc((size_t)N * 4);
  int*   cnt    = (int*)  walloc((size_t)N * 4);
  int*   rs     = (int*)  walloc((size_t)(N + 1) * 4);
  int*   cursor = (int*)  walloc((size_t)N * 4);
  void*  colv   =         walloc((size_t)E * 4);   // holds ushort (E*2) or int (E*4)
  float* pool   = (float*)walloc((size_t)G * 129 * 4);
  float* gcnt   = pool + (size_t)G * 128;
  int*   partials = (int*)walloc(256 * 4);

  // CSR + norms
  hipMemsetAsync(cnt, 0, (size_t)N * 4, stream);
  count_edges_k<<<(E + 255) / 256, 256, 0, stream>>>(dst, E, cnt);
  int nb = (N + 1023) / 1024;
  scan1_k<<<nb, 1024, 0, stream>>>(cnt, rs, partials, N);
  scan2_k<<<1, 64, 0, stream>>>(partials, nb);
  scan3_k<<<(N + 255) / 256, 256, 0, stream>>>(rs, cursor, partials, N, E);
  dinv_k<<<(N + 255) / 256, 256, 0, stream>>>(cnt, dinv, N);

  dim3 ggrid((N + 31) / 32, 2);
  int aggGrid = (N * 64 + 255) / 256;

  if (N <= 65535) {
    unsigned short* col = (unsigned short*)colv;
    fill_csr_k<unsigned short><<<(E + 255) / 256, 256, 0, stream>>>(src, dst, E, cursor, col);
    gemm_k<<<ggrid, 256, 0, stream>>>(x, W1, bufA, N);
    agg_k<unsigned short><<<aggGrid, 256, 0, stream>>>(bufA, rs, col, dinv, b1, bufB, N);
    gemm_k<<<ggrid, 256, 0, stream>>>(bufB, W2, bufA, N);
    agg_k<unsigned short><<<aggGrid, 256, 0, stream>>>(bufA, rs, col, dinv, b2, bufB, N);
  } else {
    int* col = (int*)colv;
    fill_csr_k<int><<<(E + 255) / 256, 256, 0, stream>>>(src, dst, E, cursor, col);
    gemm_k<<<ggrid, 256, 0, stream>>>(x, W1, bufA, N);
    agg_k<int><<<aggGrid, 256, 0, stream>>>(bufA, rs, col, dinv, b1, bufB, N);
    gemm_k<<<ggrid, 256, 0, stream>>>(bufB, W2, bufA, N);
    agg_k<int><<<aggGrid, 256, 0, stream>>>(bufA, rs, col, dinv, b2, bufB, N);
  }

  // mean pool + head
  hipMemsetAsync(pool, 0, (size_t)G * 129 * 4, stream);
  pool_k<<<(N + 63) / 64, 128, 0, stream>>>(bufB, bat, N, pool, gcnt);
  classify_k<<<G, 128, 0, stream>>>(pool, gcnt, Wc1, bc1, Wc2, bc2, out, NC);
}

// Round 3
// 544.067 us; speedup vs baseline: 1.1399x; 1.1399x over previous
//
#include <hip/hip_runtime.h>
#include <cstdint>
#include <cstddef>

#define CHUNK 8192   // edges per block in bucket passes (256 thr x 32)

// ---------------- fallback CSR build (N > 65535 only) ----------------
__global__ void count_edges_k(const int* __restrict__ dst, int E, int* __restrict__ cnt) {
  int e = blockIdx.x * blockDim.x + threadIdx.x;
  if (e < E) atomicAdd(&cnt[dst[e]], 1);
}

__global__ void dinv_k(const int* __restrict__ cnt, float* __restrict__ dinv, int n) {
  int i = blockIdx.x * blockDim.x + threadIdx.x;
  if (i < n) dinv[i] = rsqrtf((float)cnt[i] + 1.0f);
}

template <typename CT>
__global__ void fill_csr_k(const int* __restrict__ src, const int* __restrict__ dst, int E,
                           int* __restrict__ cursor, CT* __restrict__ col) {
  int e = blockIdx.x * blockDim.x + threadIdx.x;
  if (e < E) {
    int d = dst[e], s = src[e];
    int pos = atomicAdd(&cursor[d], 1);
    col[pos] = (CT)s;
  }
}

// ---------------- scan (rs from cnt) ----------------
__global__ void scan1_k(const int* __restrict__ cnt, int* __restrict__ rs,
                        int* __restrict__ partials, int n) {
  __shared__ int s[1024];
  int t = threadIdx.x;
  int gid = blockIdx.x * 1024 + t;
  int v = (gid < n) ? cnt[gid] : 0;
  s[t] = v;
  __syncthreads();
  for (int off = 1; off < 1024; off <<= 1) {
    int u = (t >= off) ? s[t - off] : 0;
    __syncthreads();
    s[t] += u;
    __syncthreads();
  }
  if (gid < n) rs[gid] = s[t] - v;
  if (t == 1023) partials[blockIdx.x] = s[1023];
}

__global__ void scan2_k(int* __restrict__ partials, int nb) {
  if (threadIdx.x == 0 && blockIdx.x == 0) {
    int acc = 0;
    for (int i = 0; i < nb; i++) { int v = partials[i]; partials[i] = acc; acc += v; }
  }
}

__global__ void scan3_k(int* __restrict__ rs, int* __restrict__ cursor,
                        const int* __restrict__ partials, int n, int total) {
  int gid = blockIdx.x * blockDim.x + threadIdx.x;
  if (gid < n) {
    int v = rs[gid] + partials[gid >> 10];
    rs[gid] = v;
    cursor[gid] = v;
  }
  if (gid == 0) rs[n] = total;
}

// ---------------- two-level bucket CSR build (N <= 65535) ----------------
// bucket b = dst >> 8; B = ceil(N/256) <= 256
__global__ __launch_bounds__(256) void hist_k(const int* __restrict__ dst, int E,
                                              int* __restrict__ blk_cnt, int nblk, int B) {
  __shared__ int h[256];
  int t = threadIdx.x;
  if (t < B) h[t] = 0;
  __syncthreads();
  int e0 = blockIdx.x * CHUNK;
  int e1 = e0 + CHUNK; if (e1 > E) e1 = E;
  for (int e = e0 + t; e < e1; e += 256) atomicAdd(&h[dst[e] >> 8], 1);
  __syncthreads();
  if (t < B) blk_cnt[(size_t)t * nblk + blockIdx.x] = h[t];
}

// per-bucket total + in-bucket exclusive block prefix (in place)
__global__ void bucket_prefix_k(int* __restrict__ blk_cnt, int nblk, int B,
                                int* __restrict__ bucket_tot) {
  int b = blockIdx.x * blockDim.x + threadIdx.x;
  if (b < B) {
    int* p = blk_cnt + (size_t)b * nblk;
    int acc = 0;
    for (int i = 0; i < nblk; i++) { int v = p[i]; p[i] = acc; acc += v; }
    bucket_tot[b] = acc;
  }
}

__global__ void bucket_base_k(const int* __restrict__ bucket_tot, int B,
                              int* __restrict__ bucket_base) {
  if (threadIdx.x == 0 && blockIdx.x == 0) {
    int acc = 0;
    for (int i = 0; i < B; i++) { bucket_base[i] = acc; acc += bucket_tot[i]; }
    bucket_base[B] = acc;
  }
}

// group edges by bucket into tmp, packed (src<<8)|(dst&255). Writes are
// contiguous runs per (block,bucket) -> full 64B lines, no amplification.
__global__ __launch_bounds__(256) void bucket_scatter_k(const int* __restrict__ src,
                                                        const int* __restrict__ dst, int E,
                                                        const int* __restrict__ blk_pre, int nblk,
                                                        const int* __restrict__ bucket_base, int B,
                                                        unsigned int* __restrict__ tmp) {
  __shared__ int h[256];
  __shared__ int base_s[256];
  int t = threadIdx.x;
  if (t < B) {
    h[t] = 0;
    base_s[t] = bucket_base[t] + blk_pre[(size_t)t * nblk + blockIdx.x];
  }
  __syncthreads();
  int e0 = blockIdx.x * CHUNK;
  int e1 = e0 + CHUNK; if (e1 > E) e1 = E;
  for (int e = e0 + t; e < e1; e += 256) {
    int d = dst[e];
    int b = d >> 8;
    int r = atomicAdd(&h[b], 1);
    tmp[base_s[b] + r] = ((unsigned)src[e] << 8) | (unsigned)(d & 255);
  }
}

// per-bucket degree count via LDS (no global atomics) + dinv
__global__ __launch_bounds__(256) void bucket_cnt_k(const unsigned int* __restrict__ tmp,
                                                    const int* __restrict__ bucket_base, int N,
                                                    int* __restrict__ cnt, float* __restrict__ dinv) {
  __shared__ int c[256];
  int b = blockIdx.x, t = threadIdx.x;
  c[t] = 0;
  __syncthreads();
  int s0 = bucket_base[b], s1 = bucket_base[b + 1];
  for (int i = s0 + t; i < s1; i += 256) atomicAdd(&c[tmp[i] & 255u], 1);
  __syncthreads();
  int node = (b << 8) + t;
  if (node < N) {
    int v = c[t];
    cnt[node] = v;
    dinv[node] = rsqrtf((float)v + 1.0f);
  }
}

// fine CSR fill: writes confined to ~16KB window per block (L2-resident)
__global__ __launch_bounds__(256) void bucket_fill_k(const unsigned int* __restrict__ tmp,
                                                     const int* __restrict__ bucket_base,
                                                     const int* __restrict__ rs, int N,
                                                     unsigned short* __restrict__ col) {
  __shared__ int cur[256];
  int b = blockIdx.x, t = threadIdx.x;
  int node = (b << 8) + t;
  cur[t] = (node < N) ? rs[node] : 0;
  __syncthreads();
  int s0 = bucket_base[b], s1 = bucket_base[b + 1];
  for (int i = s0 + t; i < s1; i += 256) {
    unsigned v = tmp[i];
    int pos = atomicAdd(&cur[v & 255u], 1);
    col[pos] = (unsigned short)(v >> 8);
  }
}

// ---------------- dense GEMM: C[N,128] = A[N,128] @ W[128,128] ----------------
__global__ __launch_bounds__(256) void gemm_k(const float* __restrict__ A,
                                              const float* __restrict__ W,
                                              float* __restrict__ C, int N) {
  __shared__ float Ws[128 * 64];
  __shared__ float As[32][132];
  const int c0 = blockIdx.y * 64;
  const int r0 = blockIdx.x * 32;
  {
    const float4* W4 = (const float4*)W;
    float4* Ws4 = (float4*)Ws;
    for (int idx = threadIdx.x; idx < 2048; idx += 256) {
      int k = idx >> 4;
      int c4 = idx & 15;
      Ws4[idx] = W4[k * 32 + (c0 >> 2) + c4];
    }
  }
  for (int idx = threadIdx.x; idx < 1024; idx += 256) {
    int rr = idx >> 5;
    int c4 = idx & 31;
    int r = r0 + rr;
    float4 v = make_float4(0.f, 0.f, 0.f, 0.f);
    if (r < N) v = ((const float4*)(A + (size_t)r * 128))[c4];
    *(float4*)&As[rr][c4 * 4] = v;
  }
  __syncthreads();
  const int tx = threadIdx.x & 15;
  const int ty = threadIdx.x >> 4;
  float acc[2][4] = {};
  #pragma unroll 8
  for (int k = 0; k < 128; k++) {
    float4 wv = *(const float4*)&Ws[k * 64 + tx * 4];
    float a0 = As[ty * 2 + 0][k];
    float a1 = As[ty * 2 + 1][k];
    acc[0][0] += a0 * wv.x; acc[0][1] += a0 * wv.y; acc[0][2] += a0 * wv.z; acc[0][3] += a0 * wv.w;
    acc[1][0] += a1 * wv.x; acc[1][1] += a1 * wv.y; acc[1][2] += a1 * wv.z; acc[1][3] += a1 * wv.w;
  }
  #pragma unroll
  for (int i = 0; i < 2; i++) {
    int r = r0 + ty * 2 + i;
    if (r < N) {
      float4 o = make_float4(acc[i][0], acc[i][1], acc[i][2], acc[i][3]);
      *(float4*)(C + (size_t)r * 128 + c0 + tx * 4) = o;
    }
  }
}

// ---------------- neighbor aggregation (CSR gather-reduce, one wave per node) ----------------
template <typename CT>
__global__ __launch_bounds__(256) void agg_k(const float* __restrict__ h,
                                             const int* __restrict__ rs,
                                             const CT* __restrict__ col,
                                             const float* __restrict__ dinv,
                                             const float* __restrict__ bias,
                                             float* __restrict__ out, int n) {
  int wid = (blockIdx.x * blockDim.x + threadIdx.x) >> 6;
  int lane = threadIdx.x & 63;
  if (wid >= n) return;
  float di = dinv[wid];
  const float* hrow = h + (size_t)wid * 128;
  float acc0 = hrow[lane] * di;
  float acc1 = hrow[64 + lane] * di;
  int beg = rs[wid], end = rs[wid + 1];
  for (int base = beg; base < end; base += 64) {
    int m = end - base; if (m > 64) m = 64;
    int sidx = 0; float w = 0.f;
    if (lane < m) { sidx = (int)col[base + lane]; w = dinv[sidx]; }
    for (int j = 0; j < m; j++) {
      int s = __shfl(sidx, j);
      float nv = __shfl(w, j);
      const float* hs = h + (size_t)s * 128;
      acc0 += hs[lane] * nv;
      acc1 += hs[64 + lane] * nv;
    }
  }
  out[(size_t)wid * 128 + lane] = fmaxf(acc0 * di + bias[lane], 0.f);
  out[(size_t)wid * 128 + 64 + lane] = fmaxf(acc1 * di + bias[64 + lane], 0.f);
}

// ---------------- per-graph mean pool ----------------
__global__ void pool_k(const float* __restrict__ h, const int* __restrict__ batch, int n,
                       float* __restrict__ pool, float* __restrict__ gcnt) {
  int f = threadIdx.x;
  int n0 = blockIdx.x * 64;
  if (n0 >= n) return;
  int n1 = n0 + 64; if (n1 > n) n1 = n;
  int gcur = batch[n0];
  float acc = 0.f, cacc = 0.f;
  for (int i = n0; i < n1; i++) {
    int g = batch[i];
    if (g != gcur) {
      atomicAdd(&pool[gcur * 128 + f], acc);
      if (f == 0) atomicAdd(&gcnt[gcur], cacc);
      acc = 0.f; cacc = 0.f; gcur = g;
    }
    acc += h[(size_t)i * 128 + f];
    cacc += 1.f;
  }
  atomicAdd(&pool[gcur * 128 + f], acc);
  if (f == 0) atomicAdd(&gcnt[gcur], cacc);
}

// ---------------- classifier head ----------------
__global__ void classify_k(const float* __restrict__ pool, const float* __restrict__ gcnt,
                           const float* __restrict__ Wc1, const float* __restrict__ bc1,
                           const float* __restrict__ Wc2, const float* __restrict__ bc2,
                           float* __restrict__ out, int nc) {
  __shared__ float gs[128];
  __shared__ float zs[128];
  int g = blockIdx.x, t = threadIdx.x;
  float c = gcnt[g]; if (c < 1.f) c = 1.f;
  gs[t] = pool[g * 128 + t] / c;
  __syncthreads();
  float acc = bc1[t];
  for (int k = 0; k < 128; k++) acc += gs[k] * Wc1[k * 128 + t];
  zs[t] = fmaxf(acc, 0.f);
  __syncthreads();
  if (t < nc) {
    float o = bc2[t];
    for (int k = 0; k < 128; k++) o += zs[k] * Wc2[k * nc + t];
    out[g * nc + t] = o;
  }
}

extern "C" void kernel_launch(void* const* d_in, const int* in_sizes, int n_in,
                              void* d_out, int out_size, void* d_ws, size_t ws_size,
                              hipStream_t stream) {
  const float* x   = (const float*)d_in[0];
  const int*   ei  = (const int*)d_in[1];
  const int*   bat = (const int*)d_in[2];
  const float* W1  = (const float*)d_in[3];
  const float* b1  = (const float*)d_in[4];
  const float* W2  = (const float*)d_in[5];
  const float* b2  = (const float*)d_in[6];
  const float* Wc1 = (const float*)d_in[7];
  const float* bc1 = (const float*)d_in[8];
  const float* Wc2 = (const float*)d_in[9];
  const float* bc2 = (const float*)d_in[10];
  float* out = (float*)d_out;

  const int N  = in_sizes[0] / 128;
  const int E  = in_sizes[1] / 2;
  const int NC = in_sizes[10];
  const int G  = out_size / NC;
  const int* src = ei;
  const int* dst = ei + E;
  (void)n_in; (void)ws_size;

  size_t off = 0;
  auto walloc = [&](size_t bytes) -> void* {
    void* p = (char*)d_ws + off;
    off += (bytes + 255) & ~(size_t)255;
    return p;
  };
  float* bufA = (float*)walloc((size_t)N * 128 * 4);
  float* bufB = (float*)walloc((size_t)N * 128 * 4);
  float* dinv = (float*)walloc((size_t)N * 4);
  int*   cnt  = (int*)  walloc((size_t)N * 4);
  int*   rs   = (int*)  walloc((size_t)(N + 1) * 4);
  float* pool = (float*)walloc((size_t)G * 129 * 4);
  float* gcnt = pool + (size_t)G * 128;
  int*   partials = (int*)walloc(256 * 4);

  const bool small = (N <= 65535);
  const int nb = (N + 1023) / 1024;
  dim3 ggrid((N + 31) / 32, 2);
  const int aggGrid = (N * 64 + 255) / 256;

  if (small) {
    const int B    = (N + 255) >> 8;
    const int nblk = (E + CHUNK - 1) / CHUNK;
    unsigned short* col   = (unsigned short*)walloc((size_t)E * 2);
    unsigned int*   tmp   = (unsigned int*)  walloc((size_t)E * 4);
    int* blk_cnt     = (int*)walloc((size_t)B * nblk * 4);
    int* bucket_tot  = (int*)walloc((size_t)B * 4);
    int* bucket_base = (int*)walloc((size_t)(B + 1) * 4);

    hist_k<<<nblk, 256, 0, stream>>>(dst, E, blk_cnt, nblk, B);
    bucket_prefix_k<<<(B + 255) / 256, 256, 0, stream>>>(blk_cnt, nblk, B, bucket_tot);
    bucket_base_k<<<1, 64, 0, stream>>>(bucket_tot, B, bucket_base);
    bucket_scatter_k<<<nblk, 256, 0, stream>>>(src, dst, E, blk_cnt, nblk, bucket_base, B, tmp);
    bucket_cnt_k<<<B, 256, 0, stream>>>(tmp, bucket_base, N, cnt, dinv);
    scan1_k<<<nb, 1024, 0, stream>>>(cnt, rs, partials, N);
    scan2_k<<<1, 64, 0, stream>>>(partials, nb);
    scan3_k<<<(N + 255) / 256, 256, 0, stream>>>(rs, cnt /*unused cursor slot*/, partials, N, E);
    bucket_fill_k<<<B, 256, 0, stream>>>(tmp, bucket_base, rs, N, col);

    gemm_k<<<ggrid, 256, 0, stream>>>(x, W1, bufA, N);
    agg_k<unsigned short><<<aggGrid, 256, 0, stream>>>(bufA, rs, col, dinv, b1, bufB, N);
    gemm_k<<<ggrid, 256, 0, stream>>>(bufB, W2, bufA, N);
    agg_k<unsigned short><<<aggGrid, 256, 0, stream>>>(bufA, rs, col, dinv, b2, bufB, N);
  } else {
    int* cursor = (int*)walloc((size_t)N * 4);
    int* col    = (int*)walloc((size_t)E * 4);
    hipMemsetAsync(cnt, 0, (size_t)N * 4, stream);
    count_edges_k<<<(E + 255) / 256, 256, 0, stream>>>(dst, E, cnt);
    scan1_k<<<nb, 1024, 0, stream>>>(cnt, rs, partials, N);
    scan2_k<<<1, 64, 0, stream>>>(partials, nb);
    scan3_k<<<(N + 255) / 256, 256, 0, stream>>>(rs, cursor, partials, N, E);
    dinv_k<<<(N + 255) / 256, 256, 0, stream>>>(cnt, dinv, N);
    fill_csr_k<int><<<(E + 255) / 256, 256, 0, stream>>>(src, dst, E, cursor, col);

    gemm_k<<<ggrid, 256, 0, stream>>>(x, W1, bufA, N);
    agg_k<int><<<aggGrid, 256, 0, stream>>>(bufA, rs, col, dinv, b1, bufB, N);
    gemm_k<<<ggrid, 256, 0, stream>>>(bufB, W2, bufA, N);
    agg_k<int><<<aggGrid, 256, 0, stream>>>(bufA, rs, col, dinv, b2, bufB, N);
  }

  hipMemsetAsync(pool, 0, (size_t)G * 129 * 4, stream);
  pool_k<<<(N + 63) / 64, 128, 0, stream>>>(bufB, bat, N, pool, gcnt);
  classify_k<<<G, 128, 0, stream>>>(pool, gcnt, Wc1, bc1, Wc2, bc2, out, NC);
}

// Round 4
// 480.385 us; speedup vs baseline: 1.2910x; 1.1326x over previous
//
#include <hip/hip_runtime.h>
#include <cstdint>
#include <cstddef>

#define CHUNK 8192

typedef __attribute__((ext_vector_type(8))) short short8;
typedef __attribute__((ext_vector_type(4))) float f32x4;

__device__ __forceinline__ float bf2f(unsigned short u) {
  return __uint_as_float(((unsigned)u) << 16);
}
__device__ __forceinline__ unsigned short f2bf(float f) {
  unsigned u = __float_as_uint(f);
  u += 0x7fffu + ((u >> 16) & 1u);   // round-to-nearest-even
  return (unsigned short)(u >> 16);
}

// ---------------- casts ----------------
__global__ void cast_bf_k(const float* __restrict__ in, unsigned short* __restrict__ out, int n4) {
  int i = blockIdx.x * 256 + threadIdx.x;
  if (i < n4) {
    float4 v = ((const float4*)in)[i];
    ushort4 o;
    o.x = f2bf(v.x); o.y = f2bf(v.y); o.z = f2bf(v.z); o.w = f2bf(v.w);
    ((ushort4*)out)[i] = o;
  }
}

// W[128][128] fp32 -> Wt[n][k] bf16
__global__ void transpose_w_k(const float* __restrict__ W, unsigned short* __restrict__ Wt) {
  int idx = blockIdx.x * 256 + threadIdx.x;   // grid 64
  int k = idx >> 7, n = idx & 127;
  Wt[n * 128 + k] = f2bf(W[idx]);
}

// ---------------- fallback CSR build (N > 65535) ----------------
__global__ void count_edges_k(const int* __restrict__ dst, int E, int* __restrict__ cnt) {
  int e = blockIdx.x * blockDim.x + threadIdx.x;
  if (e < E) atomicAdd(&cnt[dst[e]], 1);
}

__global__ void dinv_k(const int* __restrict__ cnt, float* __restrict__ dinv, int n) {
  int i = blockIdx.x * blockDim.x + threadIdx.x;
  if (i < n) dinv[i] = rsqrtf((float)cnt[i] + 1.0f);
}

template <typename CT>
__global__ void fill_csr_k(const int* __restrict__ src, const int* __restrict__ dst, int E,
                           int* __restrict__ cursor, CT* __restrict__ col) {
  int e = blockIdx.x * blockDim.x + threadIdx.x;
  if (e < E) {
    int d = dst[e], s = src[e];
    int pos = atomicAdd(&cursor[d], 1);
    col[pos] = (CT)s;
  }
}

// ---------------- scan ----------------
__global__ void scan1_k(const int* __restrict__ cnt, int* __restrict__ rs,
                        int* __restrict__ partials, int n) {
  __shared__ int s[1024];
  int t = threadIdx.x;
  int gid = blockIdx.x * 1024 + t;
  int v = (gid < n) ? cnt[gid] : 0;
  s[t] = v;
  __syncthreads();
  for (int off = 1; off < 1024; off <<= 1) {
    int u = (t >= off) ? s[t - off] : 0;
    __syncthreads();
    s[t] += u;
    __syncthreads();
  }
  if (gid < n) rs[gid] = s[t] - v;
  if (t == 1023) partials[blockIdx.x] = s[1023];
}

__global__ void scan2_k(int* __restrict__ partials, int nb) {
  if (threadIdx.x == 0 && blockIdx.x == 0) {
    int acc = 0;
    for (int i = 0; i < nb; i++) { int v = partials[i]; partials[i] = acc; acc += v; }
  }
}

__global__ void scan3_k(int* __restrict__ rs, int* __restrict__ cursor,
                        const int* __restrict__ partials, int n, int total) {
  int gid = blockIdx.x * blockDim.x + threadIdx.x;
  if (gid < n) {
    int v = rs[gid] + partials[gid >> 10];
    rs[gid] = v;
    cursor[gid] = v;
  }
  if (gid == 0) rs[n] = total;
}

// ---------------- two-level bucket CSR build (N <= 65535) ----------------
__global__ __launch_bounds__(256) void hist_k(const int* __restrict__ dst, int E,
                                              int* __restrict__ blk_cnt, int nblk, int B) {
  __shared__ int h[256];
  int t = threadIdx.x;
  if (t < B) h[t] = 0;
  __syncthreads();
  int e0 = blockIdx.x * CHUNK;
  int e1 = e0 + CHUNK; if (e1 > E) e1 = E;
  for (int e = e0 + t; e < e1; e += 256) atomicAdd(&h[dst[e] >> 8], 1);
  __syncthreads();
  if (t < B) blk_cnt[(size_t)t * nblk + blockIdx.x] = h[t];
}

__global__ void bucket_prefix_k(int* __restrict__ blk_cnt, int nblk, int B,
                                int* __restrict__ bucket_tot) {
  int b = blockIdx.x * blockDim.x + threadIdx.x;
  if (b < B) {
    int* p = blk_cnt + (size_t)b * nblk;
    int acc = 0;
    for (int i = 0; i < nblk; i++) { int v = p[i]; p[i] = acc; acc += v; }
    bucket_tot[b] = acc;
  }
}

__global__ void bucket_base_k(const int* __restrict__ bucket_tot, int B,
                              int* __restrict__ bucket_base) {
  if (threadIdx.x == 0 && blockIdx.x == 0) {
    int acc = 0;
    for (int i = 0; i < B; i++) { bucket_base[i] = acc; acc += bucket_tot[i]; }
    bucket_base[B] = acc;
  }
}

__global__ __launch_bounds__(256) void bucket_scatter_k(const int* __restrict__ src,
                                                        const int* __restrict__ dst, int E,
                                                        const int* __restrict__ blk_pre, int nblk,
                                                        const int* __restrict__ bucket_base, int B,
                                                        unsigned int* __restrict__ tmp) {
  __shared__ int h[256];
  __shared__ int base_s[256];
  int t = threadIdx.x;
  if (t < B) {
    h[t] = 0;
    base_s[t] = bucket_base[t] + blk_pre[(size_t)t * nblk + blockIdx.x];
  }
  __syncthreads();
  int e0 = blockIdx.x * CHUNK;
  int e1 = e0 + CHUNK; if (e1 > E) e1 = E;
  for (int e = e0 + t; e < e1; e += 256) {
    int d = dst[e];
    int b = d >> 8;
    int r = atomicAdd(&h[b], 1);
    tmp[base_s[b] + r] = ((unsigned)src[e] << 8) | (unsigned)(d & 255);
  }
}

__global__ __launch_bounds__(256) void bucket_cnt_k(const unsigned int* __restrict__ tmp,
                                                    const int* __restrict__ bucket_base, int N,
                                                    int* __restrict__ cnt, float* __restrict__ dinv) {
  __shared__ int c[256];
  int b = blockIdx.x, t = threadIdx.x;
  c[t] = 0;
  __syncthreads();
  int s0 = bucket_base[b], s1 = bucket_base[b + 1];
  for (int i = s0 + t; i < s1; i += 256) atomicAdd(&c[tmp[i] & 255u], 1);
  __syncthreads();
  int node = (b << 8) + t;
  if (node < N) {
    int v = c[t];
    cnt[node] = v;
    dinv[node] = rsqrtf((float)v + 1.0f);
  }
}

__global__ __launch_bounds__(256) void bucket_fill_k(const unsigned int* __restrict__ tmp,
                                                     const int* __restrict__ bucket_base,
                                                     const int* __restrict__ rs, int N,
                                                     unsigned short* __restrict__ col) {
  __shared__ int cur[256];
  int b = blockIdx.x, t = threadIdx.x;
  int node = (b << 8) + t;
  cur[t] = (node < N) ? rs[node] : 0;
  __syncthreads();
  int s0 = bucket_base[b], s1 = bucket_base[b + 1];
  for (int i = s0 + t; i < s1; i += 256) {
    unsigned v = tmp[i];
    int pos = atomicAdd(&cur[v & 255u], 1);
    col[pos] = (unsigned short)(v >> 8);
  }
}

// ---------------- MFMA GEMM: C[N,128](bf16) = A[N,128](bf16) @ W ----------------
// Wt is W transposed: Wt[n][k] bf16. Block = 64 rows, 4 waves x 16 rows.
// Layouts (verified m89/m91/m120): A-frag A[m=lane&15][k=quad*8+j];
// B-frag Bt[n=lane&15][k=quad*8+j]; C/D col=lane&15, row=quad*4+reg.
__global__ __launch_bounds__(256) void gemm_bf_k(const unsigned short* __restrict__ A,
                                                 const unsigned short* __restrict__ Wt,
                                                 unsigned short* __restrict__ C, int N) {
  __shared__ unsigned short Ws[128 * 136];   // pad 8: row stride 272B (16B-aligned)
  for (int idx = threadIdx.x; idx < 2048; idx += 256) {   // 2048 x 16B = 64KB? no: 32KB
    int n = idx >> 4, c = idx & 15;
    *(uint4*)&Ws[n * 136 + c * 8] = ((const uint4*)Wt)[idx];
  }
  __syncthreads();
  const int w = threadIdx.x >> 6;
  const int lane = threadIdx.x & 63;
  const int quad = lane >> 4, l16 = lane & 15;
  const int r = blockIdx.x * 64 + w * 16 + l16;
  const unsigned short* arow = A + (size_t)r * 128;
  f32x4 acc[8] = {};
  #pragma unroll
  for (int ks = 0; ks < 4; ks++) {
    short8 aF = {};
    if (r < N) aF = *(const short8*)(arow + ks * 32 + quad * 8);
    #pragma unroll
    for (int t = 0; t < 8; t++) {
      short8 bF = *(const short8*)&Ws[(t * 16 + l16) * 136 + ks * 32 + quad * 8];
      acc[t] = __builtin_amdgcn_mfma_f32_16x16x32_bf16(aF, bF, acc[t], 0, 0, 0);
    }
  }
  const int rbase = blockIdx.x * 64 + w * 16 + quad * 4;
  #pragma unroll
  for (int t = 0; t < 8; t++) {
    #pragma unroll
    for (int rg = 0; rg < 4; rg++) {
      int rr = rbase + rg;
      if (rr < N) C[(size_t)rr * 128 + t * 16 + l16] = f2bf(acc[t][rg]);
    }
  }
}

// ---------------- aggregation: bf16 gather, fp32 accumulate ----------------
// out = relu( di*(sum_s h[s]*dinv[s] + h[self]*di) + bias )
template <typename CT, bool OUTF32>
__global__ __launch_bounds__(256) void agg_bf_k(const unsigned short* __restrict__ h,
                                                const int* __restrict__ rs,
                                                const CT* __restrict__ col,
                                                const float* __restrict__ dinv,
                                                const float* __restrict__ bias,
                                                void* __restrict__ outp, int n) {
  int wid = (blockIdx.x * blockDim.x + threadIdx.x) >> 6;
  int lane = threadIdx.x & 63;
  if (wid >= n) return;
  float di = dinv[wid];
  unsigned self = ((const unsigned*)(h + (size_t)wid * 128))[lane];
  float acc0 = bf2f((unsigned short)self) * di;
  float acc1 = bf2f((unsigned short)(self >> 16)) * di;
  int beg = rs[wid], end = rs[wid + 1];
  for (int base = beg; base < end; base += 64) {
    int m = end - base; if (m > 64) m = 64;
    int sidx = 0; float w = 0.f;
    if (lane < m) { sidx = (int)col[base + lane]; w = dinv[sidx]; }
    for (int j = 0; j < m; j++) {
      int s = __shfl(sidx, j);
      float nv = __shfl(w, j);
      unsigned hv = ((const unsigned*)(h + (size_t)s * 128))[lane];
      acc0 += bf2f((unsigned short)hv) * nv;
      acc1 += bf2f((unsigned short)(hv >> 16)) * nv;
    }
  }
  float r0 = fmaxf(acc0 * di + bias[2 * lane], 0.f);
  float r1 = fmaxf(acc1 * di + bias[2 * lane + 1], 0.f);
  if (OUTF32) {
    ((float2*)outp)[(size_t)wid * 64 + lane] = make_float2(r0, r1);
  } else {
    ((unsigned*)outp)[(size_t)wid * 64 + lane] = (unsigned)f2bf(r0) | ((unsigned)f2bf(r1) << 16);
  }
}

// ---------------- per-graph mean pool ----------------
__global__ void pool_k(const float* __restrict__ h, const int* __restrict__ batch, int n,
                       float* __restrict__ pool, float* __restrict__ gcnt) {
  int f = threadIdx.x;
  int n0 = blockIdx.x * 64;
  if (n0 >= n) return;
  int n1 = n0 + 64; if (n1 > n) n1 = n;
  int gcur = batch[n0];
  float acc = 0.f, cacc = 0.f;
  for (int i = n0; i < n1; i++) {
    int g = batch[i];
    if (g != gcur) {
      atomicAdd(&pool[gcur * 128 + f], acc);
      if (f == 0) atomicAdd(&gcnt[gcur], cacc);
      acc = 0.f; cacc = 0.f; gcur = g;
    }
    acc += h[(size_t)i * 128 + f];
    cacc += 1.f;
  }
  atomicAdd(&pool[gcur * 128 + f], acc);
  if (f == 0) atomicAdd(&gcnt[gcur], cacc);
}

// ---------------- classifier head ----------------
__global__ void classify_k(const float* __restrict__ pool, const float* __restrict__ gcnt,
                           const float* __restrict__ Wc1, const float* __restrict__ bc1,
                           const float* __restrict__ Wc2, const float* __restrict__ bc2,
                           float* __restrict__ out, int nc) {
  __shared__ float gs[128];
  __shared__ float zs[128];
  int g = blockIdx.x, t = threadIdx.x;
  float c = gcnt[g]; if (c < 1.f) c = 1.f;
  gs[t] = pool[g * 128 + t] / c;
  __syncthreads();
  float acc = bc1[t];
  for (int k = 0; k < 128; k++) acc += gs[k] * Wc1[k * 128 + t];
  zs[t] = fmaxf(acc, 0.f);
  __syncthreads();
  if (t < nc) {
    float o = bc2[t];
    for (int k = 0; k < 128; k++) o += zs[k] * Wc2[k * nc + t];
    out[g * nc + t] = o;
  }
}

extern "C" void kernel_launch(void* const* d_in, const int* in_sizes, int n_in,
                              void* d_out, int out_size, void* d_ws, size_t ws_size,
                              hipStream_t stream) {
  const float* x   = (const float*)d_in[0];
  const int*   ei  = (const int*)d_in[1];
  const int*   bat = (const int*)d_in[2];
  const float* W1  = (const float*)d_in[3];
  const float* b1  = (const float*)d_in[4];
  const float* W2  = (const float*)d_in[5];
  const float* b2  = (const float*)d_in[6];
  const float* Wc1 = (const float*)d_in[7];
  const float* bc1 = (const float*)d_in[8];
  const float* Wc2 = (const float*)d_in[9];
  const float* bc2 = (const float*)d_in[10];
  float* out = (float*)d_out;

  const int N  = in_sizes[0] / 128;
  const int E  = in_sizes[1] / 2;
  const int NC = in_sizes[10];
  const int G  = out_size / NC;
  const int* src = ei;
  const int* dst = ei + E;
  (void)n_in; (void)ws_size;

  size_t off = 0;
  auto walloc = [&](size_t bytes) -> void* {
    void* p = (char*)d_ws + off;
    off += (bytes + 255) & ~(size_t)255;
    return p;
  };
  unsigned short* B1 = (unsigned short*)walloc((size_t)N * 128 * 2);  // xb -> h2b
  unsigned short* B2 = (unsigned short*)walloc((size_t)N * 128 * 2);  // h1b
  unsigned short* B3 = (unsigned short*)walloc((size_t)N * 128 * 2);  // a1b
  float* a2   = (float*)walloc((size_t)N * 128 * 4);
  unsigned short* W1t = (unsigned short*)walloc(128 * 128 * 2);
  unsigned short* W2t = (unsigned short*)walloc(128 * 128 * 2);
  float* dinv = (float*)walloc((size_t)N * 4);
  int*   cnt  = (int*)  walloc((size_t)N * 4);
  int*   rs   = (int*)  walloc((size_t)(N + 1) * 4);
  float* pool = (float*)walloc((size_t)G * 129 * 4);
  float* gcnt = pool + (size_t)G * 128;
  int*   partials = (int*)walloc(256 * 4);

  const bool small = (N <= 65535);
  const int nb = (N + 1023) / 1024;
  const int gblocks = (N + 63) / 64;
  const int aggGrid = (N * 64 + 255) / 256;

  // weight prep + x cast (independent of CSR build)
  transpose_w_k<<<64, 256, 0, stream>>>(W1, W1t);
  transpose_w_k<<<64, 256, 0, stream>>>(W2, W2t);
  cast_bf_k<<<(N * 32 + 255) / 256, 256, 0, stream>>>(x, B1, N * 32);

  if (small) {
    const int B    = (N + 255) >> 8;
    const int nblk = (E + CHUNK - 1) / CHUNK;
    unsigned short* col = (unsigned short*)walloc((size_t)E * 2);
    unsigned int*   tmp = (unsigned int*)  walloc((size_t)E * 4);
    int* blk_cnt     = (int*)walloc((size_t)B * nblk * 4);
    int* bucket_tot  = (int*)walloc((size_t)B * 4);
    int* bucket_base = (int*)walloc((size_t)(B + 1) * 4);

    hist_k<<<nblk, 256, 0, stream>>>(dst, E, blk_cnt, nblk, B);
    bucket_prefix_k<<<(B + 255) / 256, 256, 0, stream>>>(blk_cnt, nblk, B, bucket_tot);
    bucket_base_k<<<1, 64, 0, stream>>>(bucket_tot, B, bucket_base);
    bucket_scatter_k<<<nblk, 256, 0, stream>>>(src, dst, E, blk_cnt, nblk, bucket_base, B, tmp);
    bucket_cnt_k<<<B, 256, 0, stream>>>(tmp, bucket_base, N, cnt, dinv);
    scan1_k<<<nb, 1024, 0, stream>>>(cnt, rs, partials, N);
    scan2_k<<<1, 64, 0, stream>>>(partials, nb);
    scan3_k<<<(N + 255) / 256, 256, 0, stream>>>(rs, cnt, partials, N, E);
    bucket_fill_k<<<B, 256, 0, stream>>>(tmp, bucket_base, rs, N, col);

    gemm_bf_k<<<gblocks, 256, 0, stream>>>(B1, W1t, B2, N);
    agg_bf_k<unsigned short, false><<<aggGrid, 256, 0, stream>>>(B2, rs, col, dinv, b1, B3, N);
    gemm_bf_k<<<gblocks, 256, 0, stream>>>(B3, W2t, B2, N);
    agg_bf_k<unsigned short, true><<<aggGrid, 256, 0, stream>>>(B2, rs, col, dinv, b2, a2, N);
  } else {
    int* cursor = (int*)walloc((size_t)N * 4);
    int* col    = (int*)walloc((size_t)E * 4);
    hipMemsetAsync(cnt, 0, (size_t)N * 4, stream);
    count_edges_k<<<(E + 255) / 256, 256, 0, stream>>>(dst, E, cnt);
    scan1_k<<<nb, 1024, 0, stream>>>(cnt, rs, partials, N);
    scan2_k<<<1, 64, 0, stream>>>(partials, nb);
    scan3_k<<<(N + 255) / 256, 256, 0, stream>>>(rs, cursor, partials, N, E);
    dinv_k<<<(N + 255) / 256, 256, 0, stream>>>(cnt, dinv, N);
    fill_csr_k<int><<<(E + 255) / 256, 256, 0, stream>>>(src, dst, E, cursor, col);

    gemm_bf_k<<<gblocks, 256, 0, stream>>>(B1, W1t, B2, N);
    agg_bf_k<int, false><<<aggGrid, 256, 0, stream>>>(B2, rs, col, dinv, b1, B3, N);
    gemm_bf_k<<<gblocks, 256, 0, stream>>>(B3, W2t, B2, N);
    agg_bf_k<int, true><<<aggGrid, 256, 0, stream>>>(B2, rs, col, dinv, b2, a2, N);
  }

  hipMemsetAsync(pool, 0, (size_t)G * 129 * 4, stream);
  pool_k<<<(N + 63) / 64, 128, 0, stream>>>(a2, bat, N, pool, gcnt);
  classify_k<<<G, 128, 0, stream>>>(pool, gcnt, Wc1, bc1, Wc2, bc2, out, NC);
}

// Round 5
// 401.137 us; speedup vs baseline: 1.5460x; 1.1976x over previous
//
#include <hip/hip_runtime.h>
#include <cstdint>
#include <cstddef>

#define CHUNK 8192

typedef __attribute__((ext_vector_type(8))) short short8;
typedef __attribute__((ext_vector_type(4))) float f32x4;

__device__ __forceinline__ float bf2f(unsigned short u) {
  return __uint_as_float(((unsigned)u) << 16);
}
__device__ __forceinline__ unsigned short f2bf(float f) {
  unsigned u = __float_as_uint(f);
  u += 0x7fffu + ((u >> 16) & 1u);   // RNE
  return (unsigned short)(u >> 16);
}

// W[128][128] fp32 -> Wt[n][k] bf16
__global__ void transpose_w_k(const float* __restrict__ W, unsigned short* __restrict__ Wt) {
  int idx = blockIdx.x * 256 + threadIdx.x;   // grid 64
  int k = idx >> 7, n = idx & 127;
  Wt[n * 128 + k] = f2bf(W[idx]);
}

// ---------------- fallback CSR build (N > 65535) ----------------
__global__ void count_edges_k(const int* __restrict__ dst, int E, int* __restrict__ cnt) {
  int e = blockIdx.x * blockDim.x + threadIdx.x;
  if (e < E) atomicAdd(&cnt[dst[e]], 1);
}

__global__ void dinv_k(const int* __restrict__ cnt, float* __restrict__ dinv, int n) {
  int i = blockIdx.x * blockDim.x + threadIdx.x;
  if (i < n) dinv[i] = rsqrtf((float)cnt[i] + 1.0f);
}

template <typename CT>
__global__ void fill_csr_k(const int* __restrict__ src, const int* __restrict__ dst, int E,
                           int* __restrict__ cursor, CT* __restrict__ col) {
  int e = blockIdx.x * blockDim.x + threadIdx.x;
  if (e < E) {
    int d = dst[e], s = src[e];
    int pos = atomicAdd(&cursor[d], 1);
    col[pos] = (CT)s;
  }
}

// ---------------- scan ----------------
__global__ void scan1_k(const int* __restrict__ cnt, int* __restrict__ rs,
                        int* __restrict__ partials, int n) {
  __shared__ int s[1024];
  int t = threadIdx.x;
  int gid = blockIdx.x * 1024 + t;
  int v = (gid < n) ? cnt[gid] : 0;
  s[t] = v;
  __syncthreads();
  for (int off = 1; off < 1024; off <<= 1) {
    int u = (t >= off) ? s[t - off] : 0;
    __syncthreads();
    s[t] += u;
    __syncthreads();
  }
  if (gid < n) rs[gid] = s[t] - v;
  if (t == 1023) partials[blockIdx.x] = s[1023];
}

__global__ void scan2_k(int* __restrict__ partials, int nb) {
  if (threadIdx.x == 0 && blockIdx.x == 0) {
    int acc = 0;
    for (int i = 0; i < nb; i++) { int v = partials[i]; partials[i] = acc; acc += v; }
  }
}

__global__ void scan3_k(int* __restrict__ rs, int* __restrict__ cursor,
                        const int* __restrict__ partials, int n, int total) {
  int gid = blockIdx.x * blockDim.x + threadIdx.x;
  if (gid < n) {
    int v = rs[gid] + partials[gid >> 10];
    rs[gid] = v;
    cursor[gid] = v;
  }
  if (gid == 0) rs[n] = total;
}

// ---------------- two-level bucket CSR build (N <= 65535) ----------------
__global__ __launch_bounds__(256) void hist_k(const int* __restrict__ dst, int E,
                                              int* __restrict__ blk_cnt, int nblk, int B) {
  __shared__ int h[256];
  int t = threadIdx.x;
  if (t < B) h[t] = 0;
  __syncthreads();
  int e0 = blockIdx.x * CHUNK;
  int e1 = e0 + CHUNK; if (e1 > E) e1 = E;
  for (int e = e0 + t; e < e1; e += 256) atomicAdd(&h[dst[e] >> 8], 1);
  __syncthreads();
  if (t < B) blk_cnt[(size_t)t * nblk + blockIdx.x] = h[t];
}

__global__ void bucket_prefix_k(int* __restrict__ blk_cnt, int nblk, int B,
                                int* __restrict__ bucket_tot) {
  int b = blockIdx.x * blockDim.x + threadIdx.x;
  if (b < B) {
    int* p = blk_cnt + (size_t)b * nblk;
    int acc = 0;
    for (int i = 0; i < nblk; i++) { int v = p[i]; p[i] = acc; acc += v; }
    bucket_tot[b] = acc;
  }
}

__global__ void bucket_base_k(const int* __restrict__ bucket_tot, int B,
                              int* __restrict__ bucket_base) {
  if (threadIdx.x == 0 && blockIdx.x == 0) {
    int acc = 0;
    for (int i = 0; i < B; i++) { bucket_base[i] = acc; acc += bucket_tot[i]; }
    bucket_base[B] = acc;
  }
}

__global__ __launch_bounds__(256) void bucket_scatter_k(const int* __restrict__ src,
                                                        const int* __restrict__ dst, int E,
                                                        const int* __restrict__ blk_pre, int nblk,
                                                        const int* __restrict__ bucket_base, int B,
                                                        unsigned int* __restrict__ tmp) {
  __shared__ int h[256];
  __shared__ int base_s[256];
  int t = threadIdx.x;
  if (t < B) {
    h[t] = 0;
    base_s[t] = bucket_base[t] + blk_pre[(size_t)t * nblk + blockIdx.x];
  }
  __syncthreads();
  int e0 = blockIdx.x * CHUNK;
  int e1 = e0 + CHUNK; if (e1 > E) e1 = E;
  for (int e = e0 + t; e < e1; e += 256) {
    int d = dst[e];
    int b = d >> 8;
    int r = atomicAdd(&h[b], 1);
    tmp[base_s[b] + r] = ((unsigned)src[e] << 8) | (unsigned)(d & 255);
  }
}

__global__ __launch_bounds__(256) void bucket_cnt_k(const unsigned int* __restrict__ tmp,
                                                    const int* __restrict__ bucket_base, int N,
                                                    int* __restrict__ cnt, float* __restrict__ dinv) {
  __shared__ int c[256];
  int b = blockIdx.x, t = threadIdx.x;
  c[t] = 0;
  __syncthreads();
  int s0 = bucket_base[b], s1 = bucket_base[b + 1];
  for (int i = s0 + t; i < s1; i += 256) atomicAdd(&c[tmp[i] & 255u], 1);
  __syncthreads();
  int node = (b << 8) + t;
  if (node < N) {
    int v = c[t];
    cnt[node] = v;
    dinv[node] = rsqrtf((float)v + 1.0f);
  }
}

__global__ __launch_bounds__(256) void bucket_fill_k(const unsigned int* __restrict__ tmp,
                                                     const int* __restrict__ bucket_base,
                                                     const int* __restrict__ rs, int N,
                                                     unsigned short* __restrict__ col) {
  __shared__ int cur[256];
  int b = blockIdx.x, t = threadIdx.x;
  int node = (b << 8) + t;
  cur[t] = (node < N) ? rs[node] : 0;
  __syncthreads();
  int s0 = bucket_base[b], s1 = bucket_base[b + 1];
  for (int i = s0 + t; i < s1; i += 256) {
    unsigned v = tmp[i];
    int pos = atomicAdd(&cur[v & 255u], 1);
    col[pos] = (unsigned short)(v >> 8);
  }
}

// ---------------- MFMA GEMM: C[N,128](bf16) = A[N,128] @ W ----------------
// AF32: A is fp32 (x input, cast fused). Wt[n][k] bf16 staged in LDS.
// Epilogue: MFMA C-layout -> LDS (stride 132) -> coalesced dwordx4 row stores.
template <bool AF32>
__global__ __launch_bounds__(256) void gemm_bf_k(const void* __restrict__ Ap,
                                                 const unsigned short* __restrict__ Wt,
                                                 unsigned short* __restrict__ C, int N) {
  __shared__ unsigned short Ws[128 * 136];   // 34.8KB; reused as Cs in epilogue
  for (int idx = threadIdx.x; idx < 2048; idx += 256) {
    int n = idx >> 4, c = idx & 15;
    *(uint4*)&Ws[n * 136 + c * 8] = ((const uint4*)Wt)[idx];
  }
  __syncthreads();
  const int w = threadIdx.x >> 6;
  const int lane = threadIdx.x & 63;
  const int quad = lane >> 4, l16 = lane & 15;
  const int r = blockIdx.x * 64 + w * 16 + l16;
  f32x4 acc[8] = {};
  #pragma unroll
  for (int ks = 0; ks < 4; ks++) {
    short8 aF = {};
    if (r < N) {
      if (AF32) {
        const float* ar = (const float*)Ap + (size_t)r * 128 + ks * 32 + quad * 8;
        float4 u0 = *(const float4*)ar;
        float4 u1 = *(const float4*)(ar + 4);
        aF[0] = (short)f2bf(u0.x); aF[1] = (short)f2bf(u0.y);
        aF[2] = (short)f2bf(u0.z); aF[3] = (short)f2bf(u0.w);
        aF[4] = (short)f2bf(u1.x); aF[5] = (short)f2bf(u1.y);
        aF[6] = (short)f2bf(u1.z); aF[7] = (short)f2bf(u1.w);
      } else {
        aF = *(const short8*)((const unsigned short*)Ap + (size_t)r * 128 + ks * 32 + quad * 8);
      }
    }
    #pragma unroll
    for (int t = 0; t < 8; t++) {
      short8 bF = *(const short8*)&Ws[(t * 16 + l16) * 136 + ks * 32 + quad * 8];
      acc[t] = __builtin_amdgcn_mfma_f32_16x16x32_bf16(aF, bF, acc[t], 0, 0, 0);
    }
  }
  __syncthreads();                       // all Ws reads done; reuse as Cs
  unsigned short* Cs = Ws;               // 64 rows x stride 132 = 16.9KB
  const int rloc = w * 16 + quad * 4;
  #pragma unroll
  for (int t = 0; t < 8; t++)
    #pragma unroll
    for (int rg = 0; rg < 4; rg++)
      Cs[(rloc + rg) * 132 + t * 16 + l16] = f2bf(acc[t][rg]);
  __syncthreads();
  const int r0 = blockIdx.x * 64;
  for (int idx = threadIdx.x; idx < 1024; idx += 256) {
    int row = idx >> 4, c = idx & 15;
    int rr = r0 + row;
    if (rr < N) {
      uint2 a = *(uint2*)&Cs[row * 132 + c * 8];
      uint2 b = *(uint2*)&Cs[row * 132 + c * 8 + 4];
      uint4 v = make_uint4(a.x, a.y, b.x, b.y);
      ((uint4*)C)[(size_t)rr * 16 + c] = v;
    }
  }
}

// ---------------- aggregation: 16 lanes per edge, 4 edges/iteration ----------------
// wave = 1 node; group g=lane>>4 handles edge base+g; lane l=lane&15 holds feats l*8..l*8+7.
// out = relu( di*(sum_s h[s]*dinv[s] + h[self]*di) + bias )
template <typename CT, bool OUTF32>
__global__ __launch_bounds__(256) void agg4_k(const unsigned short* __restrict__ h,
                                              const int* __restrict__ rs,
                                              const CT* __restrict__ col,
                                              const float* __restrict__ dinv,
                                              const float* __restrict__ bias,
                                              void* __restrict__ outp, int n) {
  int wid = (blockIdx.x * blockDim.x + threadIdx.x) >> 6;
  int lane = threadIdx.x & 63;
  if (wid >= n) return;
  const int g = lane >> 4;
  const int l = lane & 15;
  float di = dinv[wid];
  float acc[8] = {};
  {
    uint4 sv = ((const uint4*)(h + (size_t)wid * 128))[l];
    float ws = (g == 0) ? di : 0.f;      // self loop counted once
    acc[0] = bf2f((unsigned short)sv.x) * ws;
    acc[1] = bf2f((unsigned short)(sv.x >> 16)) * ws;
    acc[2] = bf2f((unsigned short)sv.y) * ws;
    acc[3] = bf2f((unsigned short)(sv.y >> 16)) * ws;
    acc[4] = bf2f((unsigned short)sv.z) * ws;
    acc[5] = bf2f((unsigned short)(sv.z >> 16)) * ws;
    acc[6] = bf2f((unsigned short)sv.w) * ws;
    acc[7] = bf2f((unsigned short)(sv.w >> 16)) * ws;
  }
  int beg = rs[wid], end = rs[wid + 1];
  for (int base = beg; base < end; base += 4) {
    int eid = base + g;
    int s = 0; float w = 0.f;
    if (eid < end) { s = (int)col[eid]; w = dinv[s]; }
    uint4 hv = ((const uint4*)(h + (size_t)s * 128))[l];
    acc[0] += bf2f((unsigned short)hv.x) * w;
    acc[1] += bf2f((unsigned short)(hv.x >> 16)) * w;
    acc[2] += bf2f((unsigned short)hv.y) * w;
    acc[3] += bf2f((unsigned short)(hv.y >> 16)) * w;
    acc[4] += bf2f((unsigned short)hv.z) * w;
    acc[5] += bf2f((unsigned short)(hv.z >> 16)) * w;
    acc[6] += bf2f((unsigned short)hv.w) * w;
    acc[7] += bf2f((unsigned short)(hv.w >> 16)) * w;
  }
  #pragma unroll
  for (int j = 0; j < 8; j++) {
    acc[j] += __shfl_xor(acc[j], 16);
    acc[j] += __shfl_xor(acc[j], 32);
  }
  if (g == 0) {
    float4 bA = *(const float4*)(bias + l * 8);
    float4 bB = *(const float4*)(bias + l * 8 + 4);
    float r0 = fmaxf(acc[0] * di + bA.x, 0.f);
    float r1 = fmaxf(acc[1] * di + bA.y, 0.f);
    float r2 = fmaxf(acc[2] * di + bA.z, 0.f);
    float r3 = fmaxf(acc[3] * di + bA.w, 0.f);
    float r4 = fmaxf(acc[4] * di + bB.x, 0.f);
    float r5 = fmaxf(acc[5] * di + bB.y, 0.f);
    float r6 = fmaxf(acc[6] * di + bB.z, 0.f);
    float r7 = fmaxf(acc[7] * di + bB.w, 0.f);
    if (OUTF32) {
      ((float4*)outp)[(size_t)wid * 32 + l * 2]     = make_float4(r0, r1, r2, r3);
      ((float4*)outp)[(size_t)wid * 32 + l * 2 + 1] = make_float4(r4, r5, r6, r7);
    } else {
      uint4 v;
      v.x = (unsigned)f2bf(r0) | ((unsigned)f2bf(r1) << 16);
      v.y = (unsigned)f2bf(r2) | ((unsigned)f2bf(r3) << 16);
      v.z = (unsigned)f2bf(r4) | ((unsigned)f2bf(r5) << 16);
      v.w = (unsigned)f2bf(r6) | ((unsigned)f2bf(r7) << 16);
      ((uint4*)outp)[(size_t)wid * 16 + l] = v;
    }
  }
}

// ---------------- per-graph mean pool ----------------
__global__ void pool_k(const float* __restrict__ h, const int* __restrict__ batch, int n,
                       float* __restrict__ pool, float* __restrict__ gcnt) {
  int f = threadIdx.x;
  int n0 = blockIdx.x * 64;
  if (n0 >= n) return;
  int n1 = n0 + 64; if (n1 > n) n1 = n;
  int gcur = batch[n0];
  float acc = 0.f, cacc = 0.f;
  for (int i = n0; i < n1; i++) {
    int g = batch[i];
    if (g != gcur) {
      atomicAdd(&pool[gcur * 128 + f], acc);
      if (f == 0) atomicAdd(&gcnt[gcur], cacc);
      acc = 0.f; cacc = 0.f; gcur = g;
    }
    acc += h[(size_t)i * 128 + f];
    cacc += 1.f;
  }
  atomicAdd(&pool[gcur * 128 + f], acc);
  if (f == 0) atomicAdd(&gcnt[gcur], cacc);
}

// ---------------- classifier head ----------------
__global__ void classify_k(const float* __restrict__ pool, const float* __restrict__ gcnt,
                           const float* __restrict__ Wc1, const float* __restrict__ bc1,
                           const float* __restrict__ Wc2, const float* __restrict__ bc2,
                           float* __restrict__ out, int nc) {
  __shared__ float gs[128];
  __shared__ float zs[128];
  int g = blockIdx.x, t = threadIdx.x;
  float c = gcnt[g]; if (c < 1.f) c = 1.f;
  gs[t] = pool[g * 128 + t] / c;
  __syncthreads();
  float acc = bc1[t];
  for (int k = 0; k < 128; k++) acc += gs[k] * Wc1[k * 128 + t];
  zs[t] = fmaxf(acc, 0.f);
  __syncthreads();
  if (t < nc) {
    float o = bc2[t];
    for (int k = 0; k < 128; k++) o += zs[k] * Wc2[k * nc + t];
    out[g * nc + t] = o;
  }
}

extern "C" void kernel_launch(void* const* d_in, const int* in_sizes, int n_in,
                              void* d_out, int out_size, void* d_ws, size_t ws_size,
                              hipStream_t stream) {
  const float* x   = (const float*)d_in[0];
  const int*   ei  = (const int*)d_in[1];
  const int*   bat = (const int*)d_in[2];
  const float* W1  = (const float*)d_in[3];
  const float* b1  = (const float*)d_in[4];
  const float* W2  = (const float*)d_in[5];
  const float* b2  = (const float*)d_in[6];
  const float* Wc1 = (const float*)d_in[7];
  const float* bc1 = (const float*)d_in[8];
  const float* Wc2 = (const float*)d_in[9];
  const float* bc2 = (const float*)d_in[10];
  float* out = (float*)d_out;

  const int N  = in_sizes[0] / 128;
  const int E  = in_sizes[1] / 2;
  const int NC = in_sizes[10];
  const int G  = out_size / NC;
  const int* src = ei;
  const int* dst = ei + E;
  (void)n_in; (void)ws_size;

  size_t off = 0;
  auto walloc = [&](size_t bytes) -> void* {
    void* p = (char*)d_ws + off;
    off += (bytes + 255) & ~(size_t)255;
    return p;
  };
  unsigned short* B2 = (unsigned short*)walloc((size_t)N * 128 * 2);  // gemm out
  unsigned short* B3 = (unsigned short*)walloc((size_t)N * 128 * 2);  // agg1 out
  float* a2   = (float*)walloc((size_t)N * 128 * 4);
  unsigned short* W1t = (unsigned short*)walloc(128 * 128 * 2);
  unsigned short* W2t = (unsigned short*)walloc(128 * 128 * 2);
  float* dinv = (float*)walloc((size_t)N * 4);
  int*   cnt  = (int*)  walloc((size_t)N * 4);
  int*   rs   = (int*)  walloc((size_t)(N + 1) * 4);
  float* pool = (float*)walloc((size_t)G * 129 * 4);
  float* gcnt = pool + (size_t)G * 128;
  int*   partials = (int*)walloc(256 * 4);

  const bool small = (N <= 65535);
  const int nb = (N + 1023) / 1024;
  const int gblocks = (N + 63) / 64;
  const int aggGrid = (N + 3) / 4;   // 1 wave per node, 4 waves/block

  transpose_w_k<<<64, 256, 0, stream>>>(W1, W1t);
  transpose_w_k<<<64, 256, 0, stream>>>(W2, W2t);

  if (small) {
    const int B    = (N + 255) >> 8;
    const int nblk = (E + CHUNK - 1) / CHUNK;
    unsigned short* col = (unsigned short*)walloc((size_t)E * 2);
    unsigned int*   tmp = (unsigned int*)  walloc((size_t)E * 4);
    int* blk_cnt     = (int*)walloc((size_t)B * nblk * 4);
    int* bucket_tot  = (int*)walloc((size_t)B * 4);
    int* bucket_base = (int*)walloc((size_t)(B + 1) * 4);

    hist_k<<<nblk, 256, 0, stream>>>(dst, E, blk_cnt, nblk, B);
    bucket_prefix_k<<<(B + 255) / 256, 256, 0, stream>>>(blk_cnt, nblk, B, bucket_tot);
    bucket_base_k<<<1, 64, 0, stream>>>(bucket_tot, B, bucket_base);
    bucket_scatter_k<<<nblk, 256, 0, stream>>>(src, dst, E, blk_cnt, nblk, bucket_base, B, tmp);
    bucket_cnt_k<<<B, 256, 0, stream>>>(tmp, bucket_base, N, cnt, dinv);
    scan1_k<<<nb, 1024, 0, stream>>>(cnt, rs, partials, N);
    scan2_k<<<1, 64, 0, stream>>>(partials, nb);
    scan3_k<<<(N + 255) / 256, 256, 0, stream>>>(rs, cnt, partials, N, E);
    bucket_fill_k<<<B, 256, 0, stream>>>(tmp, bucket_base, rs, N, col);

    gemm_bf_k<true><<<gblocks, 256, 0, stream>>>(x, W1t, B2, N);
    agg4_k<unsigned short, false><<<aggGrid, 256, 0, stream>>>(B2, rs, col, dinv, b1, B3, N);
    gemm_bf_k<false><<<gblocks, 256, 0, stream>>>(B3, W2t, B2, N);
    agg4_k<unsigned short, true><<<aggGrid, 256, 0, stream>>>(B2, rs, col, dinv, b2, a2, N);
  } else {
    int* cursor = (int*)walloc((size_t)N * 4);
    int* col    = (int*)walloc((size_t)E * 4);
    hipMemsetAsync(cnt, 0, (size_t)N * 4, stream);
    count_edges_k<<<(E + 255) / 256, 256, 0, stream>>>(dst, E, cnt);
    scan1_k<<<nb, 1024, 0, stream>>>(cnt, rs, partials, N);
    scan2_k<<<1, 64, 0, stream>>>(partials, nb);
    scan3_k<<<(N + 255) / 256, 256, 0, stream>>>(rs, cursor, partials, N, E);
    dinv_k<<<(N + 255) / 256, 256, 0, stream>>>(cnt, dinv, N);
    fill_csr_k<int><<<(E + 255) / 256, 256, 0, stream>>>(src, dst, E, cursor, col);

    gemm_bf_k<true><<<gblocks, 256, 0, stream>>>(x, W1t, B2, N);
    agg4_k<int, false><<<aggGrid, 256, 0, stream>>>(B2, rs, col, dinv, b1, B3, N);
    gemm_bf_k<false><<<gblocks, 256, 0, stream>>>(B3, W2t, B2, N);
    agg4_k<int, true><<<aggGrid, 256, 0, stream>>>(B2, rs, col, dinv, b2, a2, N);
  }

  hipMemsetAsync(pool, 0, (size_t)G * 129 * 4, stream);
  pool_k<<<(N + 63) / 64, 128, 0, stream>>>(a2, bat, N, pool, gcnt);
  classify_k<<<G, 128, 0, stream>>>(pool, gcnt, Wc1, bc1, Wc2, bc2, out, NC);
}

// Round 6
// 319.440 us; speedup vs baseline: 1.9414x; 1.2558x over previous
//
#include <hip/hip_runtime.h>
#include <cstdint>
#include <cstddef>

#define CHUNK 4096

typedef __attribute__((ext_vector_type(8))) short short8;
typedef __attribute__((ext_vector_type(4))) float f32x4;

__device__ __forceinline__ float bf2f(unsigned short u) {
  return __uint_as_float(((unsigned)u) << 16);
}
__device__ __forceinline__ unsigned short f2bf(float f) {
  unsigned u = __float_as_uint(f);
  u += 0x7fffu + ((u >> 16) & 1u);   // RNE
  return (unsigned short)(u >> 16);
}

// both W1,W2 [128][128] fp32 -> Wt[n][k] bf16, single launch (grid 128)
__global__ void transpose2_w_k(const float* __restrict__ W1, const float* __restrict__ W2,
                               unsigned short* __restrict__ W1t, unsigned short* __restrict__ W2t) {
  int idx = blockIdx.x * 256 + threadIdx.x;
  const float* W = (idx < 16384) ? W1 : W2;
  unsigned short* Wt = (idx < 16384) ? W1t : W2t;
  int i = idx & 16383;
  int k = i >> 7, n = i & 127;
  Wt[n * 128 + k] = f2bf(W[i]);
}

// ---------------- fallback CSR build (N > 65535) ----------------
__global__ void count_edges_k(const int* __restrict__ dst, int E, int* __restrict__ cnt) {
  int e = blockIdx.x * blockDim.x + threadIdx.x;
  if (e < E) atomicAdd(&cnt[dst[e]], 1);
}

__global__ void dinv_k(const int* __restrict__ cnt, float* __restrict__ dinv, int n) {
  int i = blockIdx.x * blockDim.x + threadIdx.x;
  if (i < n) dinv[i] = rsqrtf((float)cnt[i] + 1.0f);
}

template <typename CT>
__global__ void fill_csr_k(const int* __restrict__ src, const int* __restrict__ dst, int E,
                           int* __restrict__ cursor, CT* __restrict__ col) {
  int e = blockIdx.x * blockDim.x + threadIdx.x;
  if (e < E) {
    int d = dst[e], s = src[e];
    int pos = atomicAdd(&cursor[d], 1);
    col[pos] = (CT)s;
  }
}

__global__ void scan1_k(const int* __restrict__ cnt, int* __restrict__ rs,
                        int* __restrict__ partials, int n) {
  __shared__ int s[1024];
  int t = threadIdx.x;
  int gid = blockIdx.x * 1024 + t;
  int v = (gid < n) ? cnt[gid] : 0;
  s[t] = v;
  __syncthreads();
  for (int off = 1; off < 1024; off <<= 1) {
    int u = (t >= off) ? s[t - off] : 0;
    __syncthreads();
    s[t] += u;
    __syncthreads();
  }
  if (gid < n) rs[gid] = s[t] - v;
  if (t == 1023) partials[blockIdx.x] = s[1023];
}

__global__ void scan2_k(int* __restrict__ partials, int nb) {
  if (threadIdx.x == 0 && blockIdx.x == 0) {
    int acc = 0;
    for (int i = 0; i < nb; i++) { int v = partials[i]; partials[i] = acc; acc += v; }
  }
}

__global__ void scan3_k(int* __restrict__ rs, int* __restrict__ cursor,
                        const int* __restrict__ partials, int n, int total) {
  int gid = blockIdx.x * blockDim.x + threadIdx.x;
  if (gid < n) {
    int v = rs[gid] + partials[gid >> 10];
    rs[gid] = v;
    cursor[gid] = v;
  }
  if (gid == 0) rs[n] = total;
}

// ---------------- two-level bucket CSR build (N <= 65535) ----------------
__global__ __launch_bounds__(256) void hist_k(const int* __restrict__ dst, int E,
                                              int* __restrict__ blk_cnt, int nblk, int B) {
  __shared__ int h[256];
  int t = threadIdx.x;
  if (t < B) h[t] = 0;
  __syncthreads();
  int e0 = blockIdx.x * CHUNK;
  int e1 = e0 + CHUNK; if (e1 > E) e1 = E;
  for (int e = e0 + t; e < e1; e += 256) atomicAdd(&h[dst[e] >> 8], 1);
  __syncthreads();
  if (t < B) blk_cnt[(size_t)t * nblk + blockIdx.x] = h[t];
}

// wave-parallel in-place exclusive prefix per bucket row (one wave per bucket)
__global__ __launch_bounds__(256) void bucket_prefix_k(int* __restrict__ blk_cnt, int nblk, int B,
                                                       int* __restrict__ bucket_tot) {
  int wid = (blockIdx.x * 256 + threadIdx.x) >> 6;
  int lane = threadIdx.x & 63;
  if (wid >= B) return;
  int* p = blk_cnt + (size_t)wid * nblk;
  int running = 0;
  for (int c0 = 0; c0 < nblk; c0 += 64) {
    int idx = c0 + lane;
    int orig = (idx < nblk) ? p[idx] : 0;
    int v = orig;
    #pragma unroll
    for (int off = 1; off < 64; off <<= 1) {
      int u = __shfl_up(v, off);
      if (lane >= off) v += u;
    }
    int tot = __shfl(v, 63);
    if (idx < nblk) p[idx] = running + (v - orig);
    running += tot;
  }
  if (lane == 0) bucket_tot[wid] = running;
}

// exclusive prefix over buckets (single wave)
__global__ void bucket_base_k(const int* __restrict__ bucket_tot, int B,
                              int* __restrict__ bucket_base) {
  int lane = threadIdx.x;
  int running = 0;
  for (int c0 = 0; c0 < B; c0 += 64) {
    int idx = c0 + lane;
    int orig = (idx < B) ? bucket_tot[idx] : 0;
    int v = orig;
    #pragma unroll
    for (int off = 1; off < 64; off <<= 1) {
      int u = __shfl_up(v, off);
      if (lane >= off) v += u;
    }
    int tot = __shfl(v, 63);
    if (idx < B) bucket_base[idx] = running + (v - orig);
    running += tot;
  }
  if (lane == 0) bucket_base[B] = running;
}

__global__ __launch_bounds__(256) void bucket_scatter_k(const int* __restrict__ src,
                                                        const int* __restrict__ dst, int E,
                                                        const int* __restrict__ blk_pre, int nblk,
                                                        const int* __restrict__ bucket_base, int B,
                                                        unsigned int* __restrict__ tmp) {
  __shared__ int h[256];
  __shared__ int base_s[256];
  int t = threadIdx.x;
  if (t < B) {
    h[t] = 0;
    base_s[t] = bucket_base[t] + blk_pre[(size_t)t * nblk + blockIdx.x];
  }
  __syncthreads();
  int e0 = blockIdx.x * CHUNK;
  int e1 = e0 + CHUNK; if (e1 > E) e1 = E;
  for (int e = e0 + t; e < e1; e += 256) {
    int d = dst[e];
    int b = d >> 8;
    int r = atomicAdd(&h[b], 1);
    tmp[base_s[b] + r] = ((unsigned)src[e] << 8) | (unsigned)(d & 255);
  }
}

// fused: per-bucket count + LDS scan -> rs/dinv + CSR fill (replaces cnt+scan1/2/3+fill)
__global__ __launch_bounds__(256) void bucket_cntfill_k(const unsigned int* __restrict__ tmp,
                                                        const int* __restrict__ bucket_base,
                                                        int N, int E,
                                                        float* __restrict__ dinv,
                                                        int* __restrict__ rs,
                                                        unsigned short* __restrict__ col) {
  __shared__ int c[256];
  __shared__ int cur[256];
  int b = blockIdx.x, t = threadIdx.x;
  c[t] = 0;
  __syncthreads();
  int s0 = bucket_base[b], s1 = bucket_base[b + 1];
  for (int i = s0 + t; i < s1; i += 256) atomicAdd(&c[tmp[i] & 255u], 1);
  __syncthreads();
  int v = c[t];
  cur[t] = v;
  __syncthreads();
  for (int off = 1; off < 256; off <<= 1) {   // inclusive scan
    int u = (t >= off) ? cur[t - off] : 0;
    __syncthreads();
    cur[t] += u;
    __syncthreads();
  }
  int rsv = s0 + cur[t] - v;                  // exclusive + bucket base
  int node = (b << 8) + t;
  if (node < N) {
    rs[node] = rsv;
    dinv[node] = rsqrtf((float)v + 1.0f);
  }
  if (b == 0 && t == 0) rs[N] = E;
  __syncthreads();
  cur[t] = rsv;
  __syncthreads();
  for (int i = s0 + t; i < s1; i += 256) {
    unsigned u = tmp[i];
    int pos = atomicAdd(&cur[u & 255u], 1);
    col[pos] = (unsigned short)(u >> 8);
  }
}

// ---------------- MFMA GEMM: C[N,128](bf16) = A[N,128] @ W; 128 rows/block ----------------
template <bool AF32>
__global__ __launch_bounds__(256) void gemm_bf_k(const void* __restrict__ Ap,
                                                 const unsigned short* __restrict__ Wt,
                                                 unsigned short* __restrict__ C, int N) {
  __shared__ unsigned short Ws[128 * 136];   // 34.8KB; reused as Cs (128*132=33.8KB)
  for (int idx = threadIdx.x; idx < 2048; idx += 256) {
    int n = idx >> 4, c = idx & 15;
    *(uint4*)&Ws[n * 136 + c * 8] = ((const uint4*)Wt)[idx];
  }
  __syncthreads();
  const int w = threadIdx.x >> 6;
  const int lane = threadIdx.x & 63;
  const int quad = lane >> 4, l16 = lane & 15;
  const int rb = blockIdx.x * 128 + w * 32;
  f32x4 acc[2][8] = {};
  #pragma unroll
  for (int ks = 0; ks < 4; ks++) {
    short8 aF[2];
    #pragma unroll
    for (int m = 0; m < 2; m++) {
      int r = rb + m * 16 + l16;
      short8 a = {};
      if (r < N) {
        if (AF32) {
          const float* ar = (const float*)Ap + (size_t)r * 128 + ks * 32 + quad * 8;
          float4 u0 = *(const float4*)ar;
          float4 u1 = *(const float4*)(ar + 4);
          a[0] = (short)f2bf(u0.x); a[1] = (short)f2bf(u0.y);
          a[2] = (short)f2bf(u0.z); a[3] = (short)f2bf(u0.w);
          a[4] = (short)f2bf(u1.x); a[5] = (short)f2bf(u1.y);
          a[6] = (short)f2bf(u1.z); a[7] = (short)f2bf(u1.w);
        } else {
          a = *(const short8*)((const unsigned short*)Ap + (size_t)r * 128 + ks * 32 + quad * 8);
        }
      }
      aF[m] = a;
    }
    #pragma unroll
    for (int t = 0; t < 8; t++) {
      short8 bF = *(const short8*)&Ws[(t * 16 + l16) * 136 + ks * 32 + quad * 8];
      acc[0][t] = __builtin_amdgcn_mfma_f32_16x16x32_bf16(aF[0], bF, acc[0][t], 0, 0, 0);
      acc[1][t] = __builtin_amdgcn_mfma_f32_16x16x32_bf16(aF[1], bF, acc[1][t], 0, 0, 0);
    }
  }
  __syncthreads();
  unsigned short* Cs = Ws;
  #pragma unroll
  for (int m = 0; m < 2; m++) {
    int rloc = w * 32 + m * 16 + quad * 4;
    #pragma unroll
    for (int t = 0; t < 8; t++)
      #pragma unroll
      for (int rg = 0; rg < 4; rg++)
        Cs[(rloc + rg) * 132 + t * 16 + l16] = f2bf(acc[m][t][rg]);
  }
  __syncthreads();
  const int r0 = blockIdx.x * 128;
  for (int idx = threadIdx.x; idx < 2048; idx += 256) {
    int row = idx >> 4, c = idx & 15;
    int rr = r0 + row;
    if (rr < N) {
      uint2 a = *(uint2*)&Cs[row * 132 + c * 8];
      uint2 b = *(uint2*)&Cs[row * 132 + c * 8 + 4];
      ((uint4*)C)[(size_t)rr * 16 + c] = make_uint4(a.x, a.y, b.x, b.y);
    }
  }
}

// ---------------- aggregation: 16 lanes/edge, 8 edges in flight ----------------
template <typename CT, bool OUTF32>
__global__ __launch_bounds__(256) void agg8_k(const unsigned short* __restrict__ h,
                                              const int* __restrict__ rs,
                                              const CT* __restrict__ col,
                                              const float* __restrict__ dinv,
                                              const float* __restrict__ bias,
                                              void* __restrict__ outp, int n) {
  int wid = (blockIdx.x * blockDim.x + threadIdx.x) >> 6;
  int lane = threadIdx.x & 63;
  if (wid >= n) return;
  const int g = lane >> 4;
  const int l = lane & 15;
  float di = dinv[wid];
  float acc[8];
  {
    uint4 sv = ((const uint4*)(h + (size_t)wid * 128))[l];
    float ws = (g == 0) ? di : 0.f;
    acc[0] = bf2f((unsigned short)sv.x) * ws;
    acc[1] = bf2f((unsigned short)(sv.x >> 16)) * ws;
    acc[2] = bf2f((unsigned short)sv.y) * ws;
    acc[3] = bf2f((unsigned short)(sv.y >> 16)) * ws;
    acc[4] = bf2f((unsigned short)sv.z) * ws;
    acc[5] = bf2f((unsigned short)(sv.z >> 16)) * ws;
    acc[6] = bf2f((unsigned short)sv.w) * ws;
    acc[7] = bf2f((unsigned short)(sv.w >> 16)) * ws;
  }
  int beg = rs[wid], end = rs[wid + 1];
  for (int base = beg; base < end; base += 8) {
    int e0 = base + g, e1 = base + 4 + g;
    int i0 = (e0 < end) ? e0 : end - 1;       // clamp to an already-needed row
    int i1 = (e1 < end) ? e1 : end - 1;
    int s0 = (int)col[i0], s1 = (int)col[i1];
    float w0 = (e0 < end) ? dinv[s0] : 0.f;
    float w1 = (e1 < end) ? dinv[s1] : 0.f;
    uint4 h0 = ((const uint4*)(h + (size_t)s0 * 128))[l];
    uint4 h1 = ((const uint4*)(h + (size_t)s1 * 128))[l];
    acc[0] += bf2f((unsigned short)h0.x) * w0 + bf2f((unsigned short)h1.x) * w1;
    acc[1] += bf2f((unsigned short)(h0.x >> 16)) * w0 + bf2f((unsigned short)(h1.x >> 16)) * w1;
    acc[2] += bf2f((unsigned short)h0.y) * w0 + bf2f((unsigned short)h1.y) * w1;
    acc[3] += bf2f((unsigned short)(h0.y >> 16)) * w0 + bf2f((unsigned short)(h1.y >> 16)) * w1;
    acc[4] += bf2f((unsigned short)h0.z) * w0 + bf2f((unsigned short)h1.z) * w1;
    acc[5] += bf2f((unsigned short)(h0.z >> 16)) * w0 + bf2f((unsigned short)(h1.z >> 16)) * w1;
    acc[6] += bf2f((unsigned short)h0.w) * w0 + bf2f((unsigned short)h1.w) * w1;
    acc[7] += bf2f((unsigned short)(h0.w >> 16)) * w0 + bf2f((unsigned short)(h1.w >> 16)) * w1;
  }
  #pragma unroll
  for (int j = 0; j < 8; j++) {
    acc[j] += __shfl_xor(acc[j], 16);
    acc[j] += __shfl_xor(acc[j], 32);
  }
  if (g == 0) {
    float4 bA = *(const float4*)(bias + l * 8);
    float4 bB = *(const float4*)(bias + l * 8 + 4);
    float r0 = fmaxf(acc[0] * di + bA.x, 0.f);
    float r1 = fmaxf(acc[1] * di + bA.y, 0.f);
    float r2 = fmaxf(acc[2] * di + bA.z, 0.f);
    float r3 = fmaxf(acc[3] * di + bA.w, 0.f);
    float r4 = fmaxf(acc[4] * di + bB.x, 0.f);
    float r5 = fmaxf(acc[5] * di + bB.y, 0.f);
    float r6 = fmaxf(acc[6] * di + bB.z, 0.f);
    float r7 = fmaxf(acc[7] * di + bB.w, 0.f);
    if (OUTF32) {
      ((float4*)outp)[(size_t)wid * 32 + l * 2]     = make_float4(r0, r1, r2, r3);
      ((float4*)outp)[(size_t)wid * 32 + l * 2 + 1] = make_float4(r4, r5, r6, r7);
    } else {
      uint4 v;
      v.x = (unsigned)f2bf(r0) | ((unsigned)f2bf(r1) << 16);
      v.y = (unsigned)f2bf(r2) | ((unsigned)f2bf(r3) << 16);
      v.z = (unsigned)f2bf(r4) | ((unsigned)f2bf(r5) << 16);
      v.w = (unsigned)f2bf(r6) | ((unsigned)f2bf(r7) << 16);
      ((uint4*)outp)[(size_t)wid * 16 + l] = v;
    }
  }
}

// ---------------- per-graph mean pool ----------------
__global__ void pool_k(const float* __restrict__ h, const int* __restrict__ batch, int n,
                       float* __restrict__ pool, float* __restrict__ gcnt) {
  int f = threadIdx.x;
  int n0 = blockIdx.x * 64;
  if (n0 >= n) return;
  int n1 = n0 + 64; if (n1 > n) n1 = n;
  int gcur = batch[n0];
  float acc = 0.f, cacc = 0.f;
  for (int i = n0; i < n1; i++) {
    int g = batch[i];
    if (g != gcur) {
      atomicAdd(&pool[gcur * 128 + f], acc);
      if (f == 0) atomicAdd(&gcnt[gcur], cacc);
      acc = 0.f; cacc = 0.f; gcur = g;
    }
    acc += h[(size_t)i * 128 + f];
    cacc += 1.f;
  }
  atomicAdd(&pool[gcur * 128 + f], acc);
  if (f == 0) atomicAdd(&gcnt[gcur], cacc);
}

// ---------------- classifier head ----------------
__global__ void classify_k(const float* __restrict__ pool, const float* __restrict__ gcnt,
                           const float* __restrict__ Wc1, const float* __restrict__ bc1,
                           const float* __restrict__ Wc2, const float* __restrict__ bc2,
                           float* __restrict__ out, int nc) {
  __shared__ float gs[128];
  __shared__ float zs[128];
  int g = blockIdx.x, t = threadIdx.x;
  float c = gcnt[g]; if (c < 1.f) c = 1.f;
  gs[t] = pool[g * 128 + t] / c;
  __syncthreads();
  float acc = bc1[t];
  for (int k = 0; k < 128; k++) acc += gs[k] * Wc1[k * 128 + t];
  zs[t] = fmaxf(acc, 0.f);
  __syncthreads();
  if (t < nc) {
    float o = bc2[t];
    for (int k = 0; k < 128; k++) o += zs[k] * Wc2[k * nc + t];
    out[g * nc + t] = o;
  }
}

extern "C" void kernel_launch(void* const* d_in, const int* in_sizes, int n_in,
                              void* d_out, int out_size, void* d_ws, size_t ws_size,
                              hipStream_t stream) {
  const float* x   = (const float*)d_in[0];
  const int*   ei  = (const int*)d_in[1];
  const int*   bat = (const int*)d_in[2];
  const float* W1  = (const float*)d_in[3];
  const float* b1  = (const float*)d_in[4];
  const float* W2  = (const float*)d_in[5];
  const float* b2  = (const float*)d_in[6];
  const float* Wc1 = (const float*)d_in[7];
  const float* bc1 = (const float*)d_in[8];
  const float* Wc2 = (const float*)d_in[9];
  const float* bc2 = (const float*)d_in[10];
  float* out = (float*)d_out;

  const int N  = in_sizes[0] / 128;
  const int E  = in_sizes[1] / 2;
  const int NC = in_sizes[10];
  const int G  = out_size / NC;
  const int* src = ei;
  const int* dst = ei + E;
  (void)n_in; (void)ws_size;

  size_t off = 0;
  auto walloc = [&](size_t bytes) -> void* {
    void* p = (char*)d_ws + off;
    off += (bytes + 255) & ~(size_t)255;
    return p;
  };
  unsigned short* B2 = (unsigned short*)walloc((size_t)N * 128 * 2);
  unsigned short* B3 = (unsigned short*)walloc((size_t)N * 128 * 2);
  float* a2   = (float*)walloc((size_t)N * 128 * 4);
  unsigned short* W1t = (unsigned short*)walloc(128 * 128 * 2);
  unsigned short* W2t = (unsigned short*)walloc(128 * 128 * 2);
  float* dinv = (float*)walloc((size_t)N * 4);
  int*   rs   = (int*)  walloc((size_t)(N + 1) * 4);
  float* pool = (float*)walloc((size_t)G * 129 * 4);
  float* gcnt = pool + (size_t)G * 128;

  const bool small = (N <= 65535);
  const int gblocks = (N + 127) / 128;
  const int aggGrid = (N + 3) / 4;

  transpose2_w_k<<<128, 256, 0, stream>>>(W1, W2, W1t, W2t);

  if (small) {
    const int B    = (N + 255) >> 8;
    const int nblk = (E + CHUNK - 1) / CHUNK;
    unsigned short* col = (unsigned short*)walloc((size_t)E * 2);
    unsigned int*   tmp = (unsigned int*)  walloc((size_t)E * 4);
    int* blk_cnt     = (int*)walloc((size_t)B * nblk * 4);
    int* bucket_tot  = (int*)walloc((size_t)B * 4);
    int* bucket_base = (int*)walloc((size_t)(B + 1) * 4);

    hist_k<<<nblk, 256, 0, stream>>>(dst, E, blk_cnt, nblk, B);
    bucket_prefix_k<<<(B + 3) / 4, 256, 0, stream>>>(blk_cnt, nblk, B, bucket_tot);
    bucket_base_k<<<1, 64, 0, stream>>>(bucket_tot, B, bucket_base);
    bucket_scatter_k<<<nblk, 256, 0, stream>>>(src, dst, E, blk_cnt, nblk, bucket_base, B, tmp);
    bucket_cntfill_k<<<B, 256, 0, stream>>>(tmp, bucket_base, N, E, dinv, rs, col);

    gemm_bf_k<true><<<gblocks, 256, 0, stream>>>(x, W1t, B2, N);
    agg8_k<unsigned short, false><<<aggGrid, 256, 0, stream>>>(B2, rs, col, dinv, b1, B3, N);
    gemm_bf_k<false><<<gblocks, 256, 0, stream>>>(B3, W2t, B2, N);
    agg8_k<unsigned short, true><<<aggGrid, 256, 0, stream>>>(B2, rs, col, dinv, b2, a2, N);
  } else {
    const int nb = (N + 1023) / 1024;
    int* cnt    = (int*)walloc((size_t)N * 4);
    int* cursor = (int*)walloc((size_t)N * 4);
    int* col    = (int*)walloc((size_t)E * 4);
    int* partials = (int*)walloc(256 * 4);
    hipMemsetAsync(cnt, 0, (size_t)N * 4, stream);
    count_edges_k<<<(E + 255) / 256, 256, 0, stream>>>(dst, E, cnt);
    scan1_k<<<nb, 1024, 0, stream>>>(cnt, rs, partials, N);
    scan2_k<<<1, 64, 0, stream>>>(partials, nb);
    scan3_k<<<(N + 255) / 256, 256, 0, stream>>>(rs, cursor, partials, N, E);
    dinv_k<<<(N + 255) / 256, 256, 0, stream>>>(cnt, dinv, N);
    fill_csr_k<int><<<(E + 255) / 256, 256, 0, stream>>>(src, dst, E, cursor, col);

    gemm_bf_k<true><<<gblocks, 256, 0, stream>>>(x, W1t, B2, N);
    agg8_k<int, false><<<aggGrid, 256, 0, stream>>>(B2, rs, col, dinv, b1, B3, N);
    gemm_bf_k<false><<<gblocks, 256, 0, stream>>>(B3, W2t, B2, N);
    agg8_k<int, true><<<aggGrid, 256, 0, stream>>>(B2, rs, col, dinv, b2, a2, N);
  }

  hipMemsetAsync(pool, 0, (size_t)G * 129 * 4, stream);
  pool_k<<<(N + 63) / 64, 128, 0, stream>>>(a2, bat, N, pool, gcnt);
  classify_k<<<G, 128, 0, stream>>>(pool, gcnt, Wc1, bc1, Wc2, bc2, out, NC);
}